// Round 17
// baseline (168.646 us; speedup 1.0000x reference)
//
#include <hip/hip_runtime.h>

// Masked dot-product attention. INPUTS float32, OUTPUT float32.
// B=32, Q=K=2048, D=128.
// R17: R16 fa_dyn body (8-wave, K+V dbuf LDS, 1 barrier/tile, T12 repack)
// launched at grid 512 -> TWO blocks/CU (108 VGPR -> 4 waves/SIMD; LDS
// 2x66KB=132<160KB), so barrier drains of one block hide under the other.
// Items switched to CHUNK=8 splitting (R8's correctness-verified planner
// + N-way combine) so ~550-700 items feed 512 block-slots.

using bf16   = __bf16;
using bf16x4 = __attribute__((ext_vector_type(4)))  __bf16;
using bf16x8 = __attribute__((ext_vector_type(8)))  __bf16;
using f32x4  = __attribute__((ext_vector_type(4)))  float;
using f32x16 = __attribute__((ext_vector_type(16))) float;

constexpr int BATCH = 32;
constexpr int QLEN  = 2048;
constexpr int KLEN  = 2048;
constexpr int DH    = 128;
constexpr int KVBLK = 64;      // kv tile
constexpr int NT    = KLEN / KVBLK;   // 32
constexpr int CHUNK = 8;       // kv tiles per chunk item
constexpr int MAXSLOTS = 96;

// ---- workspace layout (byte offsets) ----
constexpr size_t OFF_KB    = 0;                        // 16 MB K tiles
constexpr size_t OFF_VB    = (size_t)16 << 20;         // 16 MB V^T tiles
constexpr size_t OFF_HDR   = (size_t)32 << 20;         // [0]=n_items [1]=counter [16+2b]=slotbase [17+2b]=chunks(0=unsplit)
constexpr size_t OFF_ITEMS = OFF_HDR + 4096;           // int[1024]
constexpr size_t OFF_L0    = OFF_HDR + 65536;          // f32[32][2048]
constexpr size_t OFF_LC    = OFF_L0 + 262144;          // f32[96][2048]
constexpr size_t OFF_PO    = OFF_LC + 786432;          // slots x 1MB
constexpr size_t PO_STRIDE = (size_t)QLEN * DH * 4;    // 1 MB

union U4f { bf16x4 h; uint2 u; };

// K tile image: [64 keys][128 d] bf16, row 256B, XOR swizzle by key.
__device__ __forceinline__ int swzK(int key, int byteoff) {
  return (key * 256 + byteoff) ^ ((key & 7) << 4);
}
// V^T tile image: [128 d][64 keys] bf16, row 128B.
__device__ __forceinline__ int swzV(int d, int byteoff) {
  return (d * 128 + byteoff) ^ (((d ^ (d >> 3)) & 7) << 4);
}

__device__ __forceinline__ void gld16(const void* g, void* l) {
  __builtin_amdgcn_global_load_lds(
      (const __attribute__((address_space(1))) void*)g,
      (__attribute__((address_space(3))) void*)l, 16, 0, 0);
}

__device__ __forceinline__ unsigned cvtpk(float lo, float hi2) {
  unsigned r;
  asm("v_cvt_pk_bf16_f32 %0, %1, %2" : "=v"(r) : "v"(lo), "v"(hi2));
  return r;
}

// ---- pre-pass: swizzled K/V tiles (zero past L, skip dead) + chunk plan ----
__global__ __launch_bounds__(256)
void conv_kv(const float* __restrict__ Kg, const float* __restrict__ Vg,
             const int* __restrict__ Lg, bf16* __restrict__ KbT,
             bf16* __restrict__ VbT, int* __restrict__ hdr,
             int* __restrict__ items, int budget)
{
  if (blockIdx.x == 0 && threadIdx.x == 0) {
    int nt[32], ord[32];
    for (int b2 = 0; b2 < 32; ++b2) {
      nt[b2] = (Lg[b2] + KVBLK - 1) / KVBLK;
      ord[b2] = b2;
    }
    for (int i2 = 1; i2 < 32; ++i2) {   // insertion sort, nt desc (LPT)
      const int key = ord[i2];
      int j = i2 - 1;
      while (j >= 0 && (nt[ord[j]] < nt[key] ||
                        (nt[ord[j]] == nt[key] && ord[j] > key))) {
        ord[j + 1] = ord[j]; --j;
      }
      ord[j + 1] = key;
    }
    int used = 0, nit = 0;
    for (int r = 0; r < 32; ++r) {
      const int b2 = ord[r];
      const int n = nt[b2];
      int chunks = (n + CHUNK - 1) / CHUNK, sp = 0, base = 0;
      if (chunks > 1 && used + chunks - 1 <= budget) {
        sp = 1; base = used; used += chunks - 1;
      } else {
        chunks = 1;
      }
      hdr[16 + 2 * b2] = base;
      hdr[17 + 2 * b2] = sp ? chunks : 0;
      for (int ci = 0; ci < chunks; ++ci) {
        const int tb2 = ci * CHUNK;
        int te2 = sp ? tb2 + CHUNK : n;
        if (te2 > n) te2 = n;
        const int first = (ci == 0) ? 1 : 0;
        const int slot = (sp && ci > 0) ? base + ci - 1 : 0;
        const int enc = b2 | (tb2 << 8) | (te2 << 14) | (sp << 20) |
                        (first << 21) | (slot << 22);
        for (int qq = 0; qq < 8; ++qq) items[nit++] = enc | (qq << 5);
      }
    }
    hdr[0] = nit;   // n_items
    hdr[1] = 0;     // counter
  }

  // bulk convert: K chunks (2^20) then V chunks (2^20); skip dead tiles
  constexpr int KCH = BATCH * NT * 64 * 16;
  constexpr int VCH = BATCH * NT * 8 * 128;
  const int stride = gridDim.x * blockDim.x;
  for (int i = blockIdx.x * blockDim.x + threadIdx.x; i < KCH + VCH; i += stride) {
    if (i < KCH) {               // (b, kt, key, i8)
      const int i8  = i & 15;
      const int key = (i >> 4) & 63;
      const int kt  = (i >> 10) & 31;
      const int b   = i >> 15;
      const int Lb  = Lg[b];
      if (kt * 64 >= Lb) continue;   // tile never staged
      const int k = kt * 64 + key;
      bf16x8 val = {};
      if (k < Lb) {
        const float* src = Kg + ((size_t)b * KLEN + k) * DH + i8 * 8;
        f32x4 a = *(const f32x4*)src;
        f32x4 c = *(const f32x4*)(src + 4);
        #pragma unroll
        for (int j = 0; j < 4; ++j) { val[j] = (bf16)a[j]; val[4 + j] = (bf16)c[j]; }
      }
      *(bf16x8*)((char*)KbT + (((size_t)b * NT + kt) << 14) + swzK(key, i8 * 16)) = val;
    } else {                     // (b, kt, ko, d)
      const int j2 = i - KCH;
      const int d  = j2 & 127;
      const int ko = (j2 >> 7) & 7;
      const int kt = (j2 >> 10) & 31;
      const int b  = j2 >> 15;
      const int Lb = Lg[b];
      if (kt * 64 >= Lb) continue;   // tile never staged
      const int kb = kt * 64 + ko * 8;
      bf16x8 val = {};
      #pragma unroll
      for (int r = 0; r < 8; ++r) {
        float f = 0.f;
        if (kb + r < Lb) f = Vg[((size_t)b * KLEN + kb + r) * DH + d];
        val[r] = (bf16)f;
      }
      *(bf16x8*)((char*)VbT + (((size_t)b * NT + kt) << 14) + swzV(d, ko * 16)) = val;
    }
  }
}

// ---- persistent attention kernel: 8 waves/block, K+V dbuf, 1 barrier ----
__global__ __launch_bounds__(512, 2)
void fa_dyn(const float* __restrict__ Qg, const int* __restrict__ Lg,
            float* __restrict__ Og, const bf16* __restrict__ KbT,
            const bf16* __restrict__ VbT, const int* __restrict__ items,
            int* __restrict__ hdr, float* __restrict__ L0,
            float* __restrict__ Lc, float* __restrict__ Po)
{
  __shared__ bf16 s_k [2][KVBLK * DH];   // 32 KB, swizzled image (dbuf)
  __shared__ bf16 s_vt[2][KVBLK * DH];   // 32 KB, swizzled V^T image (dbuf)
  __shared__ int  s_item;

  const int tid  = threadIdx.x;
  const int wave = tid >> 6;            // 0..7
  const int lane = tid & 63;
  const int c    = lane & 31;
  const int hi   = lane >> 5;
  const float SC = 0.08838834764831845f * 1.4426950408889634f; // log2e/sqrt(D)

  const int n_items = hdr[0];

  for (;;) {
    if (tid == 0) s_item = atomicAdd(&hdr[1], 1);
    __syncthreads();   // broadcast + guards LDS reuse across items
    const int it = s_item;
    if (it >= n_items) return;
    const int enc   = items[it];
    const int b     = enc & 31;
    const int qp    = (enc >> 5) & 7;    // 256-row q-item index 0..7
    const int tb    = (enc >> 8) & 63;
    const int te    = (enc >> 14) & 63;
    const int sp    = (enc >> 20) & 1;
    const int first = (enc >> 21) & 1;
    const int slot  = (enc >> 22) & 127;
    const int L     = Lg[b];

    const size_t baseQ = ((size_t)b * QLEN + (size_t)qp * 256) * DH;
    const char* Kbase = (const char*)KbT + (((size_t)b * NT) << 14);
    const char* Vbase = (const char*)VbT + (((size_t)b * NT) << 14);

    auto stageK = [&](int buf, int kt) {
      const char* tile = Kbase + ((size_t)kt << 14);
      #pragma unroll
      for (int s2 = 0; s2 < 2; ++s2) {
        const int off = wave * 2048 + s2 * 1024;
        gld16(tile + off + lane * 16, (char*)&s_k[buf][0] + off);
      }
    };
    auto stageV = [&](int buf, int kt) {
      const char* tile = Vbase + ((size_t)kt << 14);
      #pragma unroll
      for (int s2 = 0; s2 < 2; ++s2) {
        const int off = wave * 2048 + s2 * 1024;
        gld16(tile + off + lane * 16, (char*)&s_vt[buf][0] + off);
      }
    };

    // Q fragments pre-scaled by SC. B-frag: col = lane&31, k = 8*hi+i.
    bf16x8 qf[8];
    {
      const float* qpp = Qg + baseQ + (size_t)(wave * 32 + c) * DH + hi * 8;
      #pragma unroll
      for (int dc = 0; dc < 8; ++dc) {
        f32x4 a = *(const f32x4*)(qpp + dc * 16);
        f32x4 bb = *(const f32x4*)(qpp + dc * 16 + 4);
        #pragma unroll
        for (int j = 0; j < 4; ++j) {
          qf[dc][j]     = (bf16)(a[j] * SC);
          qf[dc][4 + j] = (bf16)(bb[j] * SC);
        }
      }
    }

    f32x16 o[4];
    #pragma unroll
    for (int db = 0; db < 4; ++db)
      #pragma unroll
      for (int j = 0; j < 16; ++j) o[db][j] = 0.f;
    float la0 = 0.f, la1 = 0.f;

    stageK(0, tb);
    stageV(0, tb);
    __syncthreads();   // prologue drain (Q loads + K/V(tb))

    for (int kt = tb; kt < te; ++kt) {
      const int cur   = (kt - tb) & 1;
      const bool more = (kt + 1 < te);
      if (more) {                       // prefetch next tile; lands at the
        stageK(cur ^ 1, kt + 1);        // end-of-tile barrier, hidden under
        stageV(cur ^ 1, kt + 1);        // this tile's whole compute
      }

      // ---- S^T = K · Q^T (log2-prescaled) ----
      f32x16 st[2];
      __builtin_amdgcn_s_setprio(1);
      #pragma unroll
      for (int a = 0; a < 2; ++a) {
        #pragma unroll
        for (int j = 0; j < 16; ++j) st[a][j] = 0.f;
        const int key = a * 32 + c;
        #pragma unroll
        for (int dc = 0; dc < 8; ++dc) {
          bf16x8 kf = *(const bf16x8*)((const char*)&s_k[cur][0] +
                                       swzK(key, dc * 32 + hi * 16));
          st[a] = __builtin_amdgcn_mfma_f32_32x32x16_bf16(kf, qf[dc], st[a], 0, 0, 0);
        }
      }
      __builtin_amdgcn_s_setprio(0);

      // ---- fixed-m softmax: p = exp2(s), masked past L ----
      const bool partial = ((kt + 1) * KVBLK > L);
      const int k0 = kt * KVBLK;
      #pragma unroll
      for (int a = 0; a < 2; ++a)
        #pragma unroll
        for (int r = 0; r < 16; ++r) {
          float p = __builtin_amdgcn_exp2f(st[a][r]);
          if (partial) {
            const int key = k0 + a * 32 + (r & 3) + 8 * (r >> 2) + 4 * hi;
            if (key >= L) p = 0.f;
          }
          st[a][r] = p;
          if (r & 1) la1 += p; else la0 += p;
        }

      // ---- O += P · V; P-repack via cvt_pk + permlane32_swap (VALU) ----
      __builtin_amdgcn_s_setprio(1);
      #pragma unroll
      for (int kc = 0; kc < 4; ++kc) {
        const int a = kc >> 1, g = kc & 1;
        unsigned X0 = cvtpk(st[a][8 * g + 0], st[a][8 * g + 1]);
        unsigned Y0 = cvtpk(st[a][8 * g + 4], st[a][8 * g + 5]);
        unsigned X1 = cvtpk(st[a][8 * g + 2], st[a][8 * g + 3]);
        unsigned Y1 = cvtpk(st[a][8 * g + 6], st[a][8 * g + 7]);
        asm volatile("v_permlane32_swap_b32 %0, %1" : "+v"(X0), "+v"(Y0));
        asm volatile("v_permlane32_swap_b32 %0, %1" : "+v"(X1), "+v"(Y1));
        union { unsigned u[4]; bf16x8 h; } pa;
        pa.u[0] = X0; pa.u[1] = X1; pa.u[2] = Y0; pa.u[3] = Y1;
        #pragma unroll
        for (int db = 0; db < 4; ++db) {
          const int d = db * 32 + c;
          bf16x8 vb = *(const bf16x8*)((const char*)&s_vt[cur][0] +
                                       swzV(d, kc * 32 + hi * 16));
          o[db] = __builtin_amdgcn_mfma_f32_32x32x16_bf16(pa.h, vb, o[db], 0, 0, 0);
        }
      }
      __builtin_amdgcn_s_setprio(0);

      if (more) __syncthreads();   // single barrier: this tile's reads done
                                   // + next tile's K/V landed
    }

    // ---- epilogue ----
    const float l_acc = la0 + la1;
    const float l_row = l_acc + __shfl_xor(l_acc, 32);
    if (!sp) {
      float inv[16];
      #pragma unroll
      for (int j = 0; j < 16; ++j)
        inv[j] = 1.f / __shfl(l_row, (j & 3) + 8 * (j >> 2) + 4 * hi, 64);
      float* op = Og + baseQ + (size_t)(wave * 32) * DH;
      #pragma unroll
      for (int db = 0; db < 4; ++db)
        #pragma unroll
        for (int j = 0; j < 16; ++j) {
          const int row = (j & 3) + 8 * (j >> 2) + 4 * hi;
          op[(size_t)row * DH + db * 32 + c] = o[db][j] * inv[j];
        }
    } else {
      float* op = first ? Og + baseQ + (size_t)(wave * 32) * DH
                        : Po + (size_t)slot * (PO_STRIDE / 4) +
                          (size_t)(qp * 256 + wave * 32) * DH;
      #pragma unroll
      for (int db = 0; db < 4; ++db)
        #pragma unroll
        for (int j = 0; j < 16; ++j) {
          const int row = (j & 3) + 8 * (j >> 2) + 4 * hi;
          op[(size_t)row * DH + db * 32 + c] = o[db][j];
        }
      float* Lp = (first ? L0 + b * QLEN : Lc + (size_t)slot * QLEN) +
                  qp * 256 + wave * 32;
      if (hi == 0) Lp[c] = l_row;
    }
  }
}

// ---- combine: for split batches, Og = (Og + sum Po) / (L0 + sum Lc) ----
__global__ __launch_bounds__(256)
void combine(float* __restrict__ Og, const int* __restrict__ hdr,
             const float* __restrict__ L0, const float* __restrict__ Lc,
             const float* __restrict__ Po)
{
  const int total = 32 * QLEN * (DH / 4);   // (b, row, d4)
  for (int u = blockIdx.x * blockDim.x + threadIdx.x; u < total;
       u += gridDim.x * blockDim.x) {
    const int b   = u >> 16;
    const int row = (u >> 5) & 2047;
    const int d4  = u & 31;
    const int nch = hdr[17 + 2 * b];
    if (nch == 0) continue;
    const int base = hdr[16 + 2 * b];
    float l = L0[b * QLEN + row];
    const size_t og = ((size_t)b * QLEN + row) * DH + d4 * 4;
    f32x4 acc = *(const f32x4*)(Og + og);
    for (int s = 0; s < nch - 1; ++s) {
      l += Lc[(size_t)(base + s) * QLEN + row];
      f32x4 p = *(const f32x4*)(Po + (size_t)(base + s) * (PO_STRIDE / 4) +
                                (size_t)row * DH + d4 * 4);
      #pragma unroll
      for (int j = 0; j < 4; ++j) acc[j] += p[j];
    }
    const float inv = 1.f / l;
    #pragma unroll
    for (int j = 0; j < 4; ++j) acc[j] *= inv;
    *(f32x4*)(Og + og) = acc;
  }
}

// ---- fallback (tiny ws): synchronous static kernel (known-correct) ----
__global__ __launch_bounds__(256)
void fa_fwd_sync(const float* __restrict__ Qg, const float* __restrict__ Kg,
                 const float* __restrict__ Vg, const int* __restrict__ Lg,
                 float* __restrict__ Og)
{
  __shared__ bf16 s_k[KVBLK * DH];
  __shared__ bf16 s_vt[DH * KVBLK];
  const int tid = threadIdx.x, wave = tid >> 6, lane = tid & 63;
  const int c = lane & 31, hi = lane >> 5;
  const int bid = blockIdx.x, batch = bid & 31, qtile = bid >> 5;
  const int L = Lg[batch], nt = (L + KVBLK - 1) / KVBLK;
  const size_t baseQ = ((size_t)batch * QLEN + (size_t)qtile * 128) * DH;
  const size_t baseKV = (size_t)batch * KLEN * DH;
  const float SC = 0.08838834764831845f * 1.4426950408889634f;
  bf16x8 qf[8];
  {
    const float* qp = Qg + baseQ + (size_t)(wave * 32 + c) * DH + hi * 8;
    #pragma unroll
    for (int dc = 0; dc < 8; ++dc) {
      f32x4 a = *(const f32x4*)(qp + dc * 16);
      f32x4 bb = *(const f32x4*)(qp + dc * 16 + 4);
      #pragma unroll
      for (int j = 0; j < 4; ++j) { qf[dc][j] = (bf16)(a[j]*SC); qf[dc][4+j] = (bf16)(bb[j]*SC); }
    }
  }
  f32x16 o[4];
  #pragma unroll
  for (int db = 0; db < 4; ++db)
    #pragma unroll
    for (int j = 0; j < 16; ++j) o[db][j] = 0.f;
  float l_acc = 0.f;
  for (int kt = 0; kt < nt; ++kt) {
    const int k0 = kt * KVBLK;
    __syncthreads();
    #pragma unroll
    for (int s = 0; s < 4; ++s) {
      const int id = tid + 256 * s, key = id >> 4, i8 = id & 15;
      bf16x8 val = {};
      if (k0 + key < L) {
        const float* src = Kg + baseKV + (size_t)(k0 + key) * DH + i8 * 8;
        f32x4 a = *(const f32x4*)src; f32x4 bb = *(const f32x4*)(src + 4);
        #pragma unroll
        for (int j = 0; j < 4; ++j) { val[j] = (bf16)a[j]; val[4+j] = (bf16)bb[j]; }
      }
      *(bf16x8*)((char*)s_k + swzK(key, i8 * 16)) = val;
    }
    {
      const int vp4 = tid >> 4, vi8 = tid & 15;
      bf16x8 rv[4];
      #pragma unroll
      for (int s = 0; s < 4; ++s) {
        bf16x8 val = {};
        if (k0 + 4 * vp4 + s < L) {
          const float* src = Vg + baseKV + (size_t)(k0 + 4 * vp4 + s) * DH + vi8 * 8;
          f32x4 a = *(const f32x4*)src; f32x4 bb = *(const f32x4*)(src + 4);
          #pragma unroll
          for (int j = 0; j < 4; ++j) { val[j] = (bf16)a[j]; val[4+j] = (bf16)bb[j]; }
        }
        rv[s] = val;
      }
      #pragma unroll
      for (int j = 0; j < 8; ++j) {
        bf16x4 w = { rv[0][j], rv[1][j], rv[2][j], rv[3][j] };
        *(bf16x4*)((char*)s_vt + swzV(vi8 * 8 + j, vp4 * 8)) = w;
      }
    }
    __syncthreads();
    f32x16 st[2];
    #pragma unroll
    for (int a = 0; a < 2; ++a) {
      #pragma unroll
      for (int j = 0; j < 16; ++j) st[a][j] = 0.f;
      const int key = a * 32 + c;
      #pragma unroll
      for (int dc = 0; dc < 8; ++dc) {
        bf16x8 kf = *(const bf16x8*)((const char*)s_k + swzK(key, dc * 32 + hi * 16));
        st[a] = __builtin_amdgcn_mfma_f32_32x32x16_bf16(kf, qf[dc], st[a], 0, 0, 0);
      }
    }
    const bool partial = (k0 + KVBLK > L);
    #pragma unroll
    for (int a = 0; a < 2; ++a)
      #pragma unroll
      for (int r = 0; r < 16; ++r) {
        float p = __builtin_amdgcn_exp2f(st[a][r]);
        if (partial) {
          const int key = k0 + a * 32 + (r & 3) + 8 * (r >> 2) + 4 * hi;
          if (key >= L) p = 0.f;
        }
        st[a][r] = p; l_acc += p;
      }
    #pragma unroll
    for (int kc = 0; kc < 4; ++kc) {
      const int a = kc >> 1, g = kc & 1;
      bf16x4 A, Bv;
      #pragma unroll
      for (int q2 = 0; q2 < 4; ++q2) { A[q2] = (bf16)st[a][q2+8*g]; Bv[q2] = (bf16)st[a][q2+8*g+4]; }
      U4f snd; snd.h = hi ? A : Bv;
      U4f rcv;
      rcv.u.x = (unsigned)__shfl_xor((int)snd.u.x, 32);
      rcv.u.y = (unsigned)__shfl_xor((int)snd.u.y, 32);
      bf16x4 loh = hi ? rcv.h : A;
      bf16x4 hih = hi ? Bv : rcv.h;
      bf16x8 pa;
      #pragma unroll
      for (int q2 = 0; q2 < 4; ++q2) { pa[q2] = loh[q2]; pa[q2+4] = hih[q2]; }
      #pragma unroll
      for (int db = 0; db < 4; ++db) {
        const int d = db * 32 + c;
        bf16x8 vb = *(const bf16x8*)((const char*)s_vt + swzV(d, kc * 32 + hi * 16));
        o[db] = __builtin_amdgcn_mfma_f32_32x32x16_bf16(pa, vb, o[db], 0, 0, 0);
      }
    }
  }
  const float l_row = l_acc + __shfl_xor(l_acc, 32);
  float inv[16];
  #pragma unroll
  for (int j = 0; j < 16; ++j)
    inv[j] = 1.f / __shfl(l_row, (j & 3) + 8 * (j >> 2) + 4 * hi, 64);
  float* op = Og + baseQ + (size_t)(wave * 32) * DH;
  #pragma unroll
  for (int db = 0; db < 4; ++db)
    #pragma unroll
    for (int j = 0; j < 16; ++j) {
      const int row = (j & 3) + 8 * (j >> 2) + 4 * hi;
      op[(size_t)row * DH + db * 32 + c] = o[db][j] * inv[j];
    }
}

extern "C" void kernel_launch(void* const* d_in, const int* in_sizes, int n_in,
                              void* d_out, int out_size, void* d_ws, size_t ws_size,
                              hipStream_t stream) {
  const float* q = (const float*)d_in[0];
  const float* k = (const float*)d_in[1];
  const float* v = (const float*)d_in[2];
  const int* lens = (const int*)d_in[3];
  float* out = (float*)d_out;

  if (ws_size >= OFF_PO) {
    char* W = (char*)d_ws;
    bf16* KbT = (bf16*)(W + OFF_KB);
    bf16* VbT = (bf16*)(W + OFF_VB);
    int*  hdr = (int*)(W + OFF_HDR);
    int*  items = (int*)(W + OFF_ITEMS);
    float* L0 = (float*)(W + OFF_L0);
    float* Lc = (float*)(W + OFF_LC);
    float* Po = (float*)(W + OFF_PO);
    int budget = (int)((ws_size - OFF_PO) / PO_STRIDE);
    if (budget > MAXSLOTS) budget = MAXSLOTS;
    hipLaunchKernelGGL(conv_kv, dim3(4096), dim3(256), 0, stream,
                       k, v, lens, KbT, VbT, hdr, items, budget);
    hipLaunchKernelGGL(fa_dyn, dim3(512), dim3(512), 0, stream,
                       q, lens, out, KbT, VbT, items, hdr, L0, Lc, Po);
    hipLaunchKernelGGL(combine, dim3(2048), dim3(256), 0, stream,
                       out, hdr, L0, Lc, Po);
  } else {
    hipLaunchKernelGGL(fa_fwd_sync, dim3(BATCH * (QLEN / 128)), dim3(256),
                       0, stream, q, k, v, lens, out);
  }
}

// Round 18
// 88.002 us; speedup vs baseline: 1.9164x; 1.9164x over previous
//
#include <hip/hip_runtime.h>

// Masked dot-product attention. INPUTS float32, OUTPUT float32.
// B=32, Q=K=2048, D=128.
// R18 = R15 verbatim (best verified: 89.5us total / fa_dyn 76.7us).
// Structure: pre-pass converts K/V to pre-swizzled bf16 tile images in ws
// (dead tiles skipped) + half-split LPT item plan; persistent 8-wave
// (512-thr) blocks at 1 block/CU pop items from a global queue; per item:
// Q in registers (pre-scaled), K+V double-buffered in LDS via
// global_load_lds (ONE barrier per KV tile, next tile prefetched at tile
// top and hidden under the whole tile's compute), swapped-QK^T 32x32x16
// bf16 MFMA, fixed-m softmax (shift-invariant, data-bounded), in-register
// P exchange, f32 accumulate; split batches write partials merged by a
// combine pass. Reverted experiments: q-pair (spill), V-in-regs
// (uncoalesced), 2 blk/CU + CHUNK=8 (contention + partial traffic),
// counted-vmcnt (compiler drains), XCD-affine queues (7x pathology).

using bf16   = __bf16;
using bf16x4 = __attribute__((ext_vector_type(4)))  __bf16;
using bf16x8 = __attribute__((ext_vector_type(8)))  __bf16;
using f32x4  = __attribute__((ext_vector_type(4)))  float;
using f32x16 = __attribute__((ext_vector_type(16))) float;

constexpr int BATCH = 32;
constexpr int QLEN  = 2048;
constexpr int KLEN  = 2048;
constexpr int DH    = 128;
constexpr int KVBLK = 64;      // kv tile
constexpr int NT    = KLEN / KVBLK;   // 32
constexpr int SPLIT_MIN_T = 14;       // split batches with >= 14 tiles

// ---- workspace layout (byte offsets) ----
constexpr size_t OFF_KB    = 0;                        // 16 MB K tiles
constexpr size_t OFF_VB    = (size_t)16 << 20;         // 16 MB V^T tiles
constexpr size_t OFF_HDR   = (size_t)32 << 20;         // ints: [0]=n_items [1]=counter [2]=nsplit [8+s]=batch(slot)
constexpr size_t OFF_ITEMS = OFF_HDR + 4096;           // int[1024]
constexpr size_t OFF_L0    = OFF_HDR + 32768;          // f32[32][2048]
constexpr size_t OFF_L1    = OFF_L0 + ((size_t)256 << 10);
constexpr size_t OFF_PO    = OFF_L1 + ((size_t)256 << 10);
constexpr size_t PO_STRIDE = (size_t)1 << 20;          // f32[2048][128] per slot

union U4f { bf16x4 h; uint2 u; };

// K tile image: [64 keys][128 d] bf16, row 256B, XOR swizzle by key.
__device__ __forceinline__ int swzK(int key, int byteoff) {
  return (key * 256 + byteoff) ^ ((key & 7) << 4);
}
// V^T tile image: [128 d][64 keys] bf16, row 128B.
__device__ __forceinline__ int swzV(int d, int byteoff) {
  return (d * 128 + byteoff) ^ (((d ^ (d >> 3)) & 7) << 4);
}

__device__ __forceinline__ void gld16(const void* g, void* l) {
  __builtin_amdgcn_global_load_lds(
      (const __attribute__((address_space(1))) void*)g,
      (__attribute__((address_space(3))) void*)l, 16, 0, 0);
}

// ---- pre-pass: swizzled K/V tiles (zero past L, skip dead tiles) + plan ----
__global__ __launch_bounds__(256)
void conv_kv(const float* __restrict__ Kg, const float* __restrict__ Vg,
             const int* __restrict__ Lg, bf16* __restrict__ KbT,
             bf16* __restrict__ VbT, int* __restrict__ hdr,
             int* __restrict__ items, int budget)
{
  __shared__ int sh_nt[32], sh_sp[32], sh_rk[32], sh_len[64];
  if (blockIdx.x == 0) {
    const int t = threadIdx.x;
    if (t < 32) {
      const int nt = (Lg[t] + KVBLK - 1) / KVBLK;
      int rank = 0;
      for (int j = 0; j < 32; ++j) {
        const int ntj = (Lg[j] + KVBLK - 1) / KVBLK;
        rank += (ntj > nt) || (ntj == nt && j < t);
      }
      const int sp = (nt >= SPLIT_MIN_T && rank < budget) ? 1 : 0;
      sh_nt[t] = nt; sh_sp[t] = sp; sh_rk[t] = rank;
      if (sp) hdr[8 + rank] = t;
    }
    __syncthreads();
    if (t < 64) {
      const int b = t >> 1, tl = t & 1;
      const int nt = sh_nt[b], sp = sh_sp[b];
      int tb, te;
      if (sp) { const int h = nt >> 1; tb = tl ? h : 0; te = tl ? nt : h; }
      else    { tb = 0; te = tl ? 0 : nt; }
      sh_len[t] = te - tb;
    }
    __syncthreads();
    if (t < 64) {
      const int len = sh_len[t];
      if (len > 0) {
        int r = 0;   // LPT rank among nonempty chunks (len desc)
        for (int j = 0; j < 64; ++j)
          r += (sh_len[j] > len) || (sh_len[j] == len && j < t);
        const int b = t >> 1, tl = t & 1;
        const int nt = sh_nt[b], sp = sh_sp[b];
        int tb = 0, te = nt;
        if (sp) { const int h = nt >> 1; tb = tl ? h : 0; te = tl ? nt : h; }
        const int slot = sp ? sh_rk[b] : 0;
        const int tailf = sp & tl;
        #pragma unroll
        for (int qq = 0; qq < 8; ++qq)   // 8 q-items (256 rows each)
          items[r * 8 + qq] =
              b | (qq << 5) | (tb << 9) | (te << 15) | (sp << 21) |
              (tailf << 22) | (slot << 23);
      }
    }
    if (threadIdx.x == 0) {
      int ns = 0;
      for (int j = 0; j < 32; ++j) ns += sh_sp[j];
      hdr[0] = (32 + ns) * 8;    // n_items
      hdr[1] = 0;                // counter
      hdr[2] = ns;               // nsplit
    }
  }

  // bulk convert: K chunks (2^20) then V chunks (2^20); skip dead tiles
  constexpr int KCH = BATCH * NT * 64 * 16;
  constexpr int VCH = BATCH * NT * 8 * 128;
  const int stride = gridDim.x * blockDim.x;
  for (int i = blockIdx.x * blockDim.x + threadIdx.x; i < KCH + VCH; i += stride) {
    if (i < KCH) {               // (b, kt, key, i8)
      const int i8  = i & 15;
      const int key = (i >> 4) & 63;
      const int kt  = (i >> 10) & 31;
      const int b   = i >> 15;
      const int Lb  = Lg[b];
      if (kt * 64 >= Lb) continue;   // tile never staged
      const int k = kt * 64 + key;
      bf16x8 val = {};
      if (k < Lb) {
        const float* src = Kg + ((size_t)b * KLEN + k) * DH + i8 * 8;
        f32x4 a = *(const f32x4*)src;
        f32x4 c = *(const f32x4*)(src + 4);
        #pragma unroll
        for (int j = 0; j < 4; ++j) { val[j] = (bf16)a[j]; val[4 + j] = (bf16)c[j]; }
      }
      *(bf16x8*)((char*)KbT + (((size_t)b * NT + kt) << 14) + swzK(key, i8 * 16)) = val;
    } else {                     // (b, kt, ko, d)
      const int j2 = i - KCH;
      const int d  = j2 & 127;
      const int ko = (j2 >> 7) & 7;
      const int kt = (j2 >> 10) & 31;
      const int b  = j2 >> 15;
      const int Lb = Lg[b];
      if (kt * 64 >= Lb) continue;   // tile never staged
      const int kb = kt * 64 + ko * 8;
      bf16x8 val = {};
      #pragma unroll
      for (int r = 0; r < 8; ++r) {
        float f = 0.f;
        if (kb + r < Lb) f = Vg[((size_t)b * KLEN + kb + r) * DH + d];
        val[r] = (bf16)f;
      }
      *(bf16x8*)((char*)VbT + (((size_t)b * NT + kt) << 14) + swzV(d, ko * 16)) = val;
    }
  }
}

// ---- persistent attention kernel: 8 waves/block, K+V dbuf, 1 barrier ----
__global__ __launch_bounds__(512, 2)
void fa_dyn(const float* __restrict__ Qg, const int* __restrict__ Lg,
            float* __restrict__ Og, const bf16* __restrict__ KbT,
            const bf16* __restrict__ VbT, const int* __restrict__ items,
            int* __restrict__ hdr, float* __restrict__ L0,
            float* __restrict__ L1, float* __restrict__ Po)
{
  __shared__ bf16 s_k [2][KVBLK * DH];   // 32 KB, swizzled image (dbuf)
  __shared__ bf16 s_vt[2][KVBLK * DH];   // 32 KB, swizzled V^T image (dbuf)
  __shared__ int  s_item;

  const int tid  = threadIdx.x;
  const int wave = tid >> 6;            // 0..7
  const int lane = tid & 63;
  const int c    = lane & 31;
  const int hi   = lane >> 5;
  const float SC = 0.08838834764831845f * 1.4426950408889634f; // log2e/sqrt(D)

  const int n_items = hdr[0];

  for (;;) {
    if (tid == 0) s_item = atomicAdd(&hdr[1], 1);
    __syncthreads();   // broadcast + guards LDS reuse across items
    const int it = s_item;
    if (it >= n_items) return;
    const int enc  = items[it];
    const int b    = enc & 31;
    const int qp   = (enc >> 5) & 15;   // 256-row q-item index 0..7
    const int tb   = (enc >> 9) & 63;
    const int te   = (enc >> 15) & 63;
    const int sp   = (enc >> 21) & 1;
    const int tail = (enc >> 22) & 1;
    const int slot = (enc >> 23) & 31;
    const int L    = Lg[b];

    const size_t baseQ = ((size_t)b * QLEN + (size_t)qp * 256) * DH;
    const char* Kbase = (const char*)KbT + (((size_t)b * NT) << 14);
    const char* Vbase = (const char*)VbT + (((size_t)b * NT) << 14);

    auto stageK = [&](int buf, int kt) {
      const char* tile = Kbase + ((size_t)kt << 14);
      #pragma unroll
      for (int s2 = 0; s2 < 2; ++s2) {
        const int off = wave * 2048 + s2 * 1024;
        gld16(tile + off + lane * 16, (char*)&s_k[buf][0] + off);
      }
    };
    auto stageV = [&](int buf, int kt) {
      const char* tile = Vbase + ((size_t)kt << 14);
      #pragma unroll
      for (int s2 = 0; s2 < 2; ++s2) {
        const int off = wave * 2048 + s2 * 1024;
        gld16(tile + off + lane * 16, (char*)&s_vt[buf][0] + off);
      }
    };

    // Q fragments pre-scaled by SC. B-frag: col = lane&31, k = 8*hi+i.
    bf16x8 qf[8];
    {
      const float* qpp = Qg + baseQ + (size_t)(wave * 32 + c) * DH + hi * 8;
      #pragma unroll
      for (int dc = 0; dc < 8; ++dc) {
        f32x4 a = *(const f32x4*)(qpp + dc * 16);
        f32x4 bb = *(const f32x4*)(qpp + dc * 16 + 4);
        #pragma unroll
        for (int j = 0; j < 4; ++j) {
          qf[dc][j]     = (bf16)(a[j] * SC);
          qf[dc][4 + j] = (bf16)(bb[j] * SC);
        }
      }
    }

    f32x16 o[4];
    #pragma unroll
    for (int db = 0; db < 4; ++db)
      #pragma unroll
      for (int j = 0; j < 16; ++j) o[db][j] = 0.f;
    float l_acc = 0.f;

    stageK(0, tb);
    stageV(0, tb);
    __syncthreads();   // prologue drain (Q loads + K/V(tb))

    for (int kt = tb; kt < te; ++kt) {
      const int cur   = (kt - tb) & 1;
      const bool more = (kt + 1 < te);
      if (more) {                       // prefetch next tile; lands at the
        stageK(cur ^ 1, kt + 1);        // end-of-tile barrier, hidden under
        stageV(cur ^ 1, kt + 1);        // this tile's whole compute
      }

      // ---- S^T = K · Q^T (log2-prescaled) ----
      f32x16 st[2];
      __builtin_amdgcn_s_setprio(1);
      #pragma unroll
      for (int a = 0; a < 2; ++a) {
        #pragma unroll
        for (int j = 0; j < 16; ++j) st[a][j] = 0.f;
        const int key = a * 32 + c;
        #pragma unroll
        for (int dc = 0; dc < 8; ++dc) {
          bf16x8 kf = *(const bf16x8*)((const char*)&s_k[cur][0] +
                                       swzK(key, dc * 32 + hi * 16));
          st[a] = __builtin_amdgcn_mfma_f32_32x32x16_bf16(kf, qf[dc], st[a], 0, 0, 0);
        }
      }
      __builtin_amdgcn_s_setprio(0);

      // ---- fixed-m softmax: p = exp2(s), masked past L ----
      const bool partial = ((kt + 1) * KVBLK > L);
      const int k0 = kt * KVBLK;
      #pragma unroll
      for (int a = 0; a < 2; ++a)
        #pragma unroll
        for (int r = 0; r < 16; ++r) {
          float p = __builtin_amdgcn_exp2f(st[a][r]);
          if (partial) {
            const int key = k0 + a * 32 + (r & 3) + 8 * (r >> 2) + 4 * hi;
            if (key >= L) p = 0.f;
          }
          st[a][r] = p;
          l_acc += p;
        }

      // ---- O += P · V with in-register P exchange (V from dbuf cur) ----
      __builtin_amdgcn_s_setprio(1);
      #pragma unroll
      for (int kc = 0; kc < 4; ++kc) {
        const int a = kc >> 1, g = kc & 1;
        bf16x4 A, Bv;
        #pragma unroll
        for (int q2 = 0; q2 < 4; ++q2) {
          A[q2]  = (bf16)st[a][q2 + 8 * g];
          Bv[q2] = (bf16)st[a][q2 + 8 * g + 4];
        }
        U4f snd; snd.h = hi ? A : Bv;
        U4f rcv;
        rcv.u.x = (unsigned)__shfl_xor((int)snd.u.x, 32);
        rcv.u.y = (unsigned)__shfl_xor((int)snd.u.y, 32);
        bf16x4 loh = hi ? rcv.h : A;
        bf16x4 hih = hi ? Bv    : rcv.h;
        bf16x8 pa;
        #pragma unroll
        for (int q2 = 0; q2 < 4; ++q2) { pa[q2] = loh[q2]; pa[q2 + 4] = hih[q2]; }
        #pragma unroll
        for (int db = 0; db < 4; ++db) {
          const int d = db * 32 + c;
          bf16x8 vb = *(const bf16x8*)((const char*)&s_vt[cur][0] +
                                       swzV(d, kc * 32 + hi * 16));
          o[db] = __builtin_amdgcn_mfma_f32_32x32x16_bf16(pa, vb, o[db], 0, 0, 0);
        }
      }
      __builtin_amdgcn_s_setprio(0);

      if (more) __syncthreads();   // single barrier: this tile's reads done
                                   // + next tile's K/V landed
    }

    // ---- epilogue ----
    const float l_row = l_acc + __shfl_xor(l_acc, 32);
    if (!sp) {
      float inv[16];
      #pragma unroll
      for (int j = 0; j < 16; ++j)
        inv[j] = 1.f / __shfl(l_row, (j & 3) + 8 * (j >> 2) + 4 * hi, 64);
      float* op = Og + baseQ + (size_t)(wave * 32) * DH;
      #pragma unroll
      for (int db = 0; db < 4; ++db)
        #pragma unroll
        for (int j = 0; j < 16; ++j) {
          const int row = (j & 3) + 8 * (j >> 2) + 4 * hi;
          op[(size_t)row * DH + db * 32 + c] = o[db][j] * inv[j];
        }
    } else {
      float* op = tail ? Po + (size_t)slot * (PO_STRIDE / 4) +
                         (size_t)(qp * 256 + wave * 32) * DH
                       : Og + baseQ + (size_t)(wave * 32) * DH;
      #pragma unroll
      for (int db = 0; db < 4; ++db)
        #pragma unroll
        for (int j = 0; j < 16; ++j) {
          const int row = (j & 3) + 8 * (j >> 2) + 4 * hi;
          op[(size_t)row * DH + db * 32 + c] = o[db][j];
        }
      float* Lp = (tail ? L1 : L0) + slot * QLEN + qp * 256 + wave * 32;
      if (hi == 0) Lp[c] = l_row;
    }
  }
}

// ---- combine split partials: Og = (Og + Po) / (l0 + l1) ----
__global__ __launch_bounds__(256)
void combine(float* __restrict__ Og, const int* __restrict__ hdr,
             const float* __restrict__ L0, const float* __restrict__ L1,
             const float* __restrict__ Po)
{
  const int nsplit = hdr[2];
  const int total = nsplit << 16;   // (s, row2048, d4) in f32x4 units
  for (int u = blockIdx.x * blockDim.x + threadIdx.x; u < total;
       u += gridDim.x * blockDim.x) {
    const int s    = u >> 16;
    const int row  = (u >> 5) & 2047;
    const int d4   = u & 31;
    const int b    = hdr[8 + s];
    const int li   = s * QLEN + row;
    const float inv = 1.f / (L0[li] + L1[li]);
    const size_t og = ((size_t)b * QLEN + row) * DH + d4 * 4;
    const size_t po = (size_t)s * (PO_STRIDE / 4) + (size_t)row * DH + d4 * 4;
    f32x4 a = *(const f32x4*)(Og + og);
    f32x4 p = *(const f32x4*)(Po + po);
    #pragma unroll
    for (int j = 0; j < 4; ++j) a[j] = (a[j] + p[j]) * inv;
    *(f32x4*)(Og + og) = a;
  }
}

// ---- fallback (tiny ws): synchronous static kernel (known-correct) ----
__global__ __launch_bounds__(256)
void fa_fwd_sync(const float* __restrict__ Qg, const float* __restrict__ Kg,
                 const float* __restrict__ Vg, const int* __restrict__ Lg,
                 float* __restrict__ Og)
{
  __shared__ bf16 s_k[KVBLK * DH];
  __shared__ bf16 s_vt[DH * KVBLK];
  const int tid = threadIdx.x, wave = tid >> 6, lane = tid & 63;
  const int c = lane & 31, hi = lane >> 5;
  const int bid = blockIdx.x, batch = bid & 31, qtile = bid >> 5;
  const int L = Lg[batch], nt = (L + KVBLK - 1) / KVBLK;
  const size_t baseQ = ((size_t)batch * QLEN + (size_t)qtile * 128) * DH;
  const size_t baseKV = (size_t)batch * KLEN * DH;
  const float SC = 0.08838834764831845f * 1.4426950408889634f;
  bf16x8 qf[8];
  {
    const float* qp = Qg + baseQ + (size_t)(wave * 32 + c) * DH + hi * 8;
    #pragma unroll
    for (int dc = 0; dc < 8; ++dc) {
      f32x4 a = *(const f32x4*)(qp + dc * 16);
      f32x4 bb = *(const f32x4*)(qp + dc * 16 + 4);
      #pragma unroll
      for (int j = 0; j < 4; ++j) { qf[dc][j] = (bf16)(a[j]*SC); qf[dc][4+j] = (bf16)(bb[j]*SC); }
    }
  }
  f32x16 o[4];
  #pragma unroll
  for (int db = 0; db < 4; ++db)
    #pragma unroll
    for (int j = 0; j < 16; ++j) o[db][j] = 0.f;
  float l_acc = 0.f;
  for (int kt = 0; kt < nt; ++kt) {
    const int k0 = kt * KVBLK;
    __syncthreads();
    #pragma unroll
    for (int s = 0; s < 4; ++s) {
      const int id = tid + 256 * s, key = id >> 4, i8 = id & 15;
      bf16x8 val = {};
      if (k0 + key < L) {
        const float* src = Kg + baseKV + (size_t)(k0 + key) * DH + i8 * 8;
        f32x4 a = *(const f32x4*)src; f32x4 bb = *(const f32x4*)(src + 4);
        #pragma unroll
        for (int j = 0; j < 4; ++j) { val[j] = (bf16)a[j]; val[4+j] = (bf16)bb[j]; }
      }
      *(bf16x8*)((char*)s_k + swzK(key, i8 * 16)) = val;
    }
    {
      const int vp4 = tid >> 4, vi8 = tid & 15;
      bf16x8 rv[4];
      #pragma unroll
      for (int s = 0; s < 4; ++s) {
        bf16x8 val = {};
        if (k0 + 4 * vp4 + s < L) {
          const float* src = Vg + baseKV + (size_t)(k0 + 4 * vp4 + s) * DH + vi8 * 8;
          f32x4 a = *(const f32x4*)src; f32x4 bb = *(const f32x4*)(src + 4);
          #pragma unroll
          for (int j = 0; j < 4; ++j) { val[j] = (bf16)a[j]; val[4+j] = (bf16)bb[j]; }
        }
        rv[s] = val;
      }
      #pragma unroll
      for (int j = 0; j < 8; ++j) {
        bf16x4 w = { rv[0][j], rv[1][j], rv[2][j], rv[3][j] };
        *(bf16x4*)((char*)s_vt + swzV(vi8 * 8 + j, vp4 * 8)) = w;
      }
    }
    __syncthreads();
    f32x16 st[2];
    #pragma unroll
    for (int a = 0; a < 2; ++a) {
      #pragma unroll
      for (int j = 0; j < 16; ++j) st[a][j] = 0.f;
      const int key = a * 32 + c;
      #pragma unroll
      for (int dc = 0; dc < 8; ++dc) {
        bf16x8 kf = *(const bf16x8*)((const char*)s_k + swzK(key, dc * 32 + hi * 16));
        st[a] = __builtin_amdgcn_mfma_f32_32x32x16_bf16(kf, qf[dc], st[a], 0, 0, 0);
      }
    }
    const bool partial = (k0 + KVBLK > L);
    #pragma unroll
    for (int a = 0; a < 2; ++a)
      #pragma unroll
      for (int r = 0; r < 16; ++r) {
        float p = __builtin_amdgcn_exp2f(st[a][r]);
        if (partial) {
          const int key = k0 + a * 32 + (r & 3) + 8 * (r >> 2) + 4 * hi;
          if (key >= L) p = 0.f;
        }
        st[a][r] = p; l_acc += p;
      }
    #pragma unroll
    for (int kc = 0; kc < 4; ++kc) {
      const int a = kc >> 1, g = kc & 1;
      bf16x4 A, Bv;
      #pragma unroll
      for (int q2 = 0; q2 < 4; ++q2) { A[q2] = (bf16)st[a][q2+8*g]; Bv[q2] = (bf16)st[a][q2+8*g+4]; }
      U4f snd; snd.h = hi ? A : Bv;
      U4f rcv;
      rcv.u.x = (unsigned)__shfl_xor((int)snd.u.x, 32);
      rcv.u.y = (unsigned)__shfl_xor((int)snd.u.y, 32);
      bf16x4 loh = hi ? rcv.h : A;
      bf16x4 hih = hi ? Bv : rcv.h;
      bf16x8 pa;
      #pragma unroll
      for (int q2 = 0; q2 < 4; ++q2) { pa[q2] = loh[q2]; pa[q2+4] = hih[q2]; }
      #pragma unroll
      for (int db = 0; db < 4; ++db) {
        const int d = db * 32 + c;
        bf16x8 vb = *(const bf16x8*)((const char*)s_vt + swzV(d, kc * 32 + hi * 16));
        o[db] = __builtin_amdgcn_mfma_f32_32x32x16_bf16(pa, vb, o[db], 0, 0, 0);
      }
    }
  }
  const float l_row = l_acc + __shfl_xor(l_acc, 32);
  float inv[16];
  #pragma unroll
  for (int j = 0; j < 16; ++j)
    inv[j] = 1.f / __shfl(l_row, (j & 3) + 8 * (j >> 2) + 4 * hi, 64);
  float* op = Og + baseQ + (size_t)(wave * 32) * DH;
  #pragma unroll
  for (int db = 0; db < 4; ++db)
    #pragma unroll
    for (int j = 0; j < 16; ++j) {
      const int row = (j & 3) + 8 * (j >> 2) + 4 * hi;
      op[(size_t)row * DH + db * 32 + c] = o[db][j] * inv[j];
    }
}

extern "C" void kernel_launch(void* const* d_in, const int* in_sizes, int n_in,
                              void* d_out, int out_size, void* d_ws, size_t ws_size,
                              hipStream_t stream) {
  const float* q = (const float*)d_in[0];
  const float* k = (const float*)d_in[1];
  const float* v = (const float*)d_in[2];
  const int* lens = (const int*)d_in[3];
  float* out = (float*)d_out;

  if (ws_size >= OFF_L0) {
    char* W = (char*)d_ws;
    bf16* KbT = (bf16*)(W + OFF_KB);
    bf16* VbT = (bf16*)(W + OFF_VB);
    int*  hdr = (int*)(W + OFF_HDR);
    int*  items = (int*)(W + OFF_ITEMS);
    float* L0 = (float*)(W + OFF_L0);
    float* L1 = (float*)(W + OFF_L1);
    float* Po = (float*)(W + OFF_PO);
    int budget = 0;
    if (ws_size >= OFF_PO + PO_STRIDE)
      budget = (int)((ws_size - OFF_PO) / PO_STRIDE);
    if (budget > 32) budget = 32;
    hipLaunchKernelGGL(conv_kv, dim3(4096), dim3(256), 0, stream,
                       k, v, lens, KbT, VbT, hdr, items, budget);
    hipLaunchKernelGGL(fa_dyn, dim3(256), dim3(512), 0, stream,
                       q, lens, out, KbT, VbT, items, hdr, L0, L1, Po);
    hipLaunchKernelGGL(combine, dim3(1024), dim3(256), 0, stream,
                       out, hdr, L0, L1, Po);
  } else {
    hipLaunchKernelGGL(fa_fwd_sync, dim3(BATCH * (QLEN / 128)), dim3(256),
                       0, stream, q, k, v, lens, out);
  }
}